// Round 1
// baseline (613.746 us; speedup 1.0000x reference)
//
#include <hip/hip_runtime.h>

#define B 4
#define N_ALL 8192
#define N_VOX 4096
#define S_PTS 1024
#define K_SAMPLE 32
#define R2 0.04f

#define FPS_T 256                 // 4 waves = exactly 1 wave per SIMD
#define NPAIR 8                   // 8 vf2 pairs = 16 points per thread
#define CONS_BLOCKS 256           // 256 blocks * 4 waves = 1024 waves; wave W serves s=W, all 4 batches
#define PUB_CHUNK 128             // publish progress every 128 FPS steps (8 fences total)

typedef float vf2 __attribute__((ext_vector_type(2)));

// Key = (dist_bits << 32) | ~idx, reinterpreted as double.
// dist in [0, 1e10] -> positive finite double, so v_max_f64 == u64 max.
// Keys unique (idx embedded); equal dists -> lowest idx (max ~idx) ==
// jnp.argmax tie-break.
__device__ __forceinline__ double mk_key(float v, unsigned int ilo) {
    return __longlong_as_double(
        ((unsigned long long)__float_as_uint(v) << 32) | ilo);
}

// Wave64 max via DPP + v_max_f64. Result valid in lane 63.
// old=0 for sourceless lanes -> +0.0 key, loses to every real key.
__device__ __forceinline__ double wave_key_max_f64(double k) {
    unsigned long long ku = __double_as_longlong(k);
#define DPP_RED(ctrl)                                                              \
    {                                                                              \
        unsigned int lo = (unsigned int)ku;                                        \
        unsigned int hi = (unsigned int)(ku >> 32);                                \
        unsigned int nlo =                                                         \
            (unsigned int)__builtin_amdgcn_update_dpp(0, (int)lo, ctrl, 0xf, 0xf, false); \
        unsigned int nhi =                                                         \
            (unsigned int)__builtin_amdgcn_update_dpp(0, (int)hi, ctrl, 0xf, 0xf, false); \
        double nk = __longlong_as_double(((unsigned long long)nhi << 32) | nlo);   \
        double cur = fmax(__longlong_as_double(ku), nk);                           \
        ku = __double_as_longlong(cur);                                            \
    }
    DPP_RED(0x111);  // row_shr:1
    DPP_RED(0x112);  // row_shr:2
    DPP_RED(0x114);  // row_shr:4
    DPP_RED(0x118);  // row_shr:8
    DPP_RED(0x142);  // row_bcast:15
    DPP_RED(0x143);  // row_bcast:31 -> lane 63 = all-64 max
#undef DPP_RED
    return __longlong_as_double(ku);
}

// ---------------------------------------------------------------------------
// Ball query + grouping for step s = W, all 4 batches. One wave per s.
// WAIT variant: spin-sleeps on per-batch progress counters (agent-scope
// relaxed atomic loads; one acquire fence after all waits), reads the FPS
// index from g_idx, gathers query coords/normals from the voxel arrays and
// writes out_xyz/out_normals itself. Arithmetic of the d2 scan is byte-
// identical to the previously-verified kernel (absmax 0.0).
// ---------------------------------------------------------------------------
template <bool WAIT>
__device__ void consumer_body(
    const int W,
    const float* __restrict__ xyz_all,
    const float* __restrict__ normals,
    const float* __restrict__ xyz_voxel,
    const float* __restrict__ normals_voxel,
    float* __restrict__ out_xyz,
    float* __restrict__ out_normals,
    float* __restrict__ out_feat,
    float* __restrict__ out_featn,
    const int* __restrict__ g_idx,
    const int* __restrict__ prog,
    int (*__restrict__ sidx)[K_SAMPLE])
{
#pragma clang fp contract(off)
    const int wid = threadIdx.x >> 6;
    const int lane = threadIdx.x & 63;
    const int s = W;

    if constexpr (WAIT) {
        const int need = s + 1;
        for (int b = 0; b < B; b++) {
            int cur;
            while ((cur = __hip_atomic_load(&prog[b], __ATOMIC_RELAXED,
                                            __HIP_MEMORY_SCOPE_AGENT)) < need) {
                if (need - cur > 2 * PUB_CHUNK) __builtin_amdgcn_s_sleep(127);
                else                            __builtin_amdgcn_s_sleep(32);
            }
        }
        __threadfence();   // acquire side: g_idx stores ordered before prog
    }

    for (int b = 0; b < B; b++) {
        const float* xyz = xyz_all + (size_t)b * N_ALL * 3;
        const float* nrm = normals + (size_t)b * N_ALL * 3;

        float qx, qy, qz;
        if constexpr (WAIT) {
            const int idx = g_idx[b * S_PTS + s];
            const float* pv = xyz_voxel + ((size_t)b * N_VOX + idx) * 3;
            const float* nv = normals_voxel + ((size_t)b * N_VOX + idx) * 3;
            qx = pv[0]; qy = pv[1]; qz = pv[2];
            if (lane < 3) {
                out_xyz[(b * S_PTS + s) * 3 + lane]     = pv[lane];
                out_normals[(b * S_PTS + s) * 3 + lane] = nv[lane];
            }
        } else {
            const float* pv = out_xyz + (b * S_PTS + s) * 3;
            qx = pv[0]; qy = pv[1]; qz = pv[2];
        }
        const float qq = __fadd_rn(__fadd_rn(__fmul_rn(qx, qx), __fmul_rn(qy, qy)),
                                   __fmul_rn(qz, qz));

        int cnt = 0;
        for (int c = 0; c < N_ALL / 64 && cnt < K_SAMPLE; c++) {
            const int i = c * 64 + lane;
            const float px = xyz[i * 3 + 0];
            const float py = xyz[i * 3 + 1];
            const float pz = xyz[i * 3 + 2];
            const float pp = __fadd_rn(__fadd_rn(__fmul_rn(px, px), __fmul_rn(py, py)),
                                       __fmul_rn(pz, pz));
            const float dt = __fadd_rn(__fadd_rn(__fmul_rn(qx, px), __fmul_rn(qy, py)),
                                       __fmul_rn(qz, pz));
            const float d2 = __fsub_rn(__fadd_rn(qq, pp), __fmul_rn(2.0f, dt));
            const bool hit = d2 < R2;
            const unsigned long long mask = __ballot(hit);
            if (hit) {
                int pos = cnt + __popcll(mask & ((1ull << lane) - 1ull));
                if (pos < K_SAMPLE) sidx[wid][pos] = i;
            }
            cnt += (int)__popcll(mask);
        }
        __syncthreads();

        if (lane < K_SAMPLE) {
            int idxj;
            if (cnt == 0)        idxj = 0;
            else if (lane < cnt) idxj = sidx[wid][lane];
            else                 idxj = sidx[wid][0];

            const float px = xyz[idxj * 3 + 0];
            const float py = xyz[idxj * 3 + 1];
            const float pz = xyz[idxj * 3 + 2];
            const float rx = __fsub_rn(px, qx);
            const float ry = __fsub_rn(py, qy);
            const float rz = __fsub_rn(pz, qz);

            const int o3 = ((b * 3) * S_PTS + s) * K_SAMPLE + lane;
            out_feat[o3 + 0 * 32768] = rx;
            out_feat[o3 + 1 * 32768] = ry;
            out_feat[o3 + 2 * 32768] = rz;

            const float nx = nrm[idxj * 3 + 0];
            const float ny = nrm[idxj * 3 + 1];
            const float nz = nrm[idxj * 3 + 2];

            const int o4 = ((b * 6) * S_PTS + s) * K_SAMPLE + lane;
            out_featn[o4 + 0 * 32768] = rx;
            out_featn[o4 + 1 * 32768] = ry;
            out_featn[o4 + 2 * 32768] = rz;
            out_featn[o4 + 3 * 32768] = nx;
            out_featn[o4 + 4 * 32768] = ny;
            out_featn[o4 + 5 * 32768] = nz;
        }
        __syncthreads();   // sidx reused by next batch iteration
    }
}

// ---------------------------------------------------------------------------
// Fused kernel. Blocks 0..3: FPS producers (inner loop bit-identical to the
// verified R4 structure: 16 pts/thread register-resident, exact distance
// update with contraction off, f64-key DPP wave reduce, double-buffered LDS
// partials, one barrier/iter). OVERLAP adds: per-step g_idx store + a
// release fence + agent-scope progress store every PUB_CHUNK steps.
// Blocks 4..: consumers (see above).
// Co-residency: 260 blocks x ~68.8KB LDS -> 2 blocks/CU -> 512 slots >= 260,
// so ALL blocks resident regardless of dispatch order -> no deadlock.
// ---------------------------------------------------------------------------
template <bool OVERLAP>
__global__ __launch_bounds__(FPS_T, 1) void fused_fps_bq_kernel(
    const float* __restrict__ xyz_voxel,
    const float* __restrict__ normals_voxel,
    const float* __restrict__ xyz_all,
    const float* __restrict__ normals,
    float* __restrict__ out_xyz,      // (B, S, 3)
    float* __restrict__ out_normals,  // (B, S, 3)
    float* __restrict__ out_feat,     // (B, 3, S, K)
    float* __restrict__ out_featn,    // (B, 6, S, K)
    int* __restrict__ g_idx,          // (B, S) published FPS indices
    int* __restrict__ prog)           // (B) progress counters (pre-zeroed)
{
#pragma clang fp contract(off)
    __shared__ float4 sp[N_VOX];                       // 64 KB
    __shared__ int fps_idx_s[S_PTS];
    __shared__ alignas(16) unsigned long long s_part[2][FPS_T / 64];
    __shared__ int sidx[4][K_SAMPLE];

    if (blockIdx.x >= B) {
        // Consumer block: wave wid serves step s = (blockIdx.x-B)*4 + wid.
        consumer_body<true>((blockIdx.x - B) * 4 + (threadIdx.x >> 6),
                            xyz_all, normals, xyz_voxel, normals_voxel,
                            out_xyz, out_normals, out_feat, out_featn,
                            g_idx, prog, sidx);
        return;
    }

    __builtin_amdgcn_s_setprio(1);    // protect FPS issue vs co-resident consumers

    const int b = blockIdx.x;
    const int t = threadIdx.x;
    const int wid = t >> 6;    // 0..3
    const int lane = t & 63;
    const int boff = b * S_PTS;

    const float* xyz = xyz_voxel + (size_t)b * N_VOX * 3;
    for (int i = t; i < N_VOX; i += FPS_T) {
        float x = xyz[i * 3 + 0];
        float y = xyz[i * 3 + 1];
        float z = xyz[i * 3 + 2];
        sp[i] = make_float4(x, y, z, 0.0f);
    }
    __syncthreads();

    // Pair jp holds global points (2jp)*256 + t (lo) and (2jp+1)*256 + t (hi).
    vf2 px2[NPAIR], py2[NPAIR], pz2[NPAIR], dist2[NPAIR];
    unsigned int ilo[2 * NPAIR];
#pragma unroll
    for (int jp = 0; jp < NPAIR; jp++) {
        float4 a = sp[t + (2 * jp) * FPS_T];
        float4 c = sp[t + (2 * jp + 1) * FPS_T];
        px2[jp] = vf2{a.x, c.x};
        py2[jp] = vf2{a.y, c.y};
        pz2[jp] = vf2{a.z, c.z};
        dist2[jp] = vf2{1e10f, 1e10f};
        ilo[2 * jp]     = ~(unsigned int)((2 * jp) * FPS_T + t);
        ilo[2 * jp + 1] = ~(unsigned int)((2 * jp + 1) * FPS_T + t);
    }

    if (t == 0) {
        fps_idx_s[0] = 0;
        if constexpr (OVERLAP) g_idx[boff] = 0;
    }
    float4 c0 = sp[0];
    float lx = c0.x, ly = c0.y, lz = c0.z;

    for (int step = 1; step < S_PTS; step++) {
        double kk[2 * NPAIR];
#pragma unroll
        for (int jp = 0; jp < NPAIR; jp++) {
            vf2 dx = px2[jp] - lx;
            vf2 dy = py2[jp] - ly;
            vf2 dz = pz2[jp] - lz;
            vf2 d = (dx * dx + dy * dy) + dz * dz;
            vf2 dm = dist2[jp];
            dm.x = fminf(dm.x, d.x);
            dm.y = fminf(dm.y, d.y);
            dist2[jp] = dm;
            kk[2 * jp]     = mk_key(dm.x, ilo[2 * jp]);
            kk[2 * jp + 1] = mk_key(dm.y, ilo[2 * jp + 1]);
        }
        // Local tree over 16 keys: 15 v_max_f64, depth 4.
        double m0 = fmax(fmax(kk[0], kk[1]),   fmax(kk[2], kk[3]));
        double m1 = fmax(fmax(kk[4], kk[5]),   fmax(kk[6], kk[7]));
        double m2 = fmax(fmax(kk[8], kk[9]),   fmax(kk[10], kk[11]));
        double m3 = fmax(fmax(kk[12], kk[13]), fmax(kk[14], kk[15]));
        double a0 = fmax(fmax(m0, m1), fmax(m2, m3));
        // One DPP wave reduce per SIMD (result in lane 63).
        a0 = wave_key_max_f64(a0);

        const int buf = step & 1;
        if (lane == 63)
            s_part[buf][wid] = (unsigned long long)__double_as_longlong(a0);
        __syncthreads();
        // 4 partials: one ds_read_b128 pair + 3 v_max_f64, all threads.
        double2 q0 = *((const double2*)&s_part[buf][0]);
        double2 q1 = *((const double2*)&s_part[buf][2]);
        double p0 = fmax(fmax(q0.x, q0.y), fmax(q1.x, q1.y));
        int besti = (int)(~(unsigned int)(unsigned long long)__double_as_longlong(p0))
                    & (N_VOX - 1);
        float4 cb = sp[besti];               // broadcast b128 read
        lx = cb.x; ly = cb.y; lz = cb.z;
        if (t == 0) {
            fps_idx_s[step] = besti;
            if constexpr (OVERLAP) {
                g_idx[boff + step] = besti;          // fire-and-forget
                if ((step & (PUB_CHUNK - 1)) == (PUB_CHUNK - 1)) {
                    __threadfence();                  // release: drain + L2 wb
                    __hip_atomic_store(&prog[b], step + 1, __ATOMIC_RELAXED,
                                       __HIP_MEMORY_SCOPE_AGENT);
                }
            }
        }
        // Double-buffered partials -> one barrier per iteration.
    }

    if constexpr (!OVERLAP) {
        __syncthreads();
        for (int i = t; i < S_PTS; i += FPS_T) {
            int idx = fps_idx_s[i];
            int o = (b * S_PTS + i) * 3;
            float4 c = sp[idx];
            out_xyz[o + 0] = c.x;
            out_xyz[o + 1] = c.y;
            out_xyz[o + 2] = c.z;
            const float* nv = normals_voxel + ((size_t)b * N_VOX + idx) * 3;
            out_normals[o + 0] = nv[0];
            out_normals[o + 1] = nv[1];
            out_normals[o + 2] = nv[2];
        }
    }
}

// Fallback (ws too small): plain ball-query kernel after sequential FPS.
__global__ __launch_bounds__(256) void ballquery_fallback_kernel(
    const float* __restrict__ xyz_all,
    const float* __restrict__ normals,
    const float* __restrict__ xyz_voxel,
    const float* __restrict__ normals_voxel,
    float* __restrict__ out_xyz,
    float* __restrict__ out_normals,
    float* __restrict__ out_feat,
    float* __restrict__ out_featn)
{
    __shared__ int sidx[4][K_SAMPLE];
    consumer_body<false>(blockIdx.x * 4 + (threadIdx.x >> 6),
                         xyz_all, normals, xyz_voxel, normals_voxel,
                         out_xyz, out_normals, out_feat, out_featn,
                         nullptr, nullptr, sidx);
}

extern "C" void kernel_launch(void* const* d_in, const int* in_sizes, int n_in,
                              void* d_out, int out_size, void* d_ws, size_t ws_size,
                              hipStream_t stream) {
    const float* xyz_all       = (const float*)d_in[0];
    const float* normals       = (const float*)d_in[1];
    const float* xyz_voxel     = (const float*)d_in[2];
    const float* normals_voxel = (const float*)d_in[3];

    float* out = (float*)d_out;
    float* out_xyz     = out;           // (4, 1024, 3)     = 12288
    float* out_normals = out + 12288;   // (4, 1024, 3)     = 12288
    float* out_feat    = out + 24576;   // (4, 3, 1024, 32) = 393216
    float* out_featn   = out + 417792;  // (4, 6, 1024, 32) = 786432

    const size_t need = (size_t)B * S_PTS * sizeof(int) + B * sizeof(int); // 16400 B
    const bool use_ws = ws_size >= need;

    if (use_ws) {
        int* g_idx = (int*)d_ws;                       // (B, S)
        int* prog  = g_idx + B * S_PTS;                // (B)
        hipMemsetAsync(prog, 0, B * sizeof(int), stream);
        fused_fps_bq_kernel<true><<<B + CONS_BLOCKS, FPS_T, 0, stream>>>(
            xyz_voxel, normals_voxel, xyz_all, normals,
            out_xyz, out_normals, out_feat, out_featn, g_idx, prog);
    } else {
        fused_fps_bq_kernel<false><<<B, FPS_T, 0, stream>>>(
            xyz_voxel, normals_voxel, xyz_all, normals,
            out_xyz, out_normals, out_feat, out_featn, nullptr, nullptr);
        ballquery_fallback_kernel<<<CONS_BLOCKS, 256, 0, stream>>>(
            xyz_all, normals, xyz_voxel, normals_voxel,
            out_xyz, out_normals, out_feat, out_featn);
    }
}